// Round 8
// baseline (4251.240 us; speedup 1.0000x reference)
//
#include <hip/hip_runtime.h>
#include <math.h>

#define Bn 64
#define Hn 1024
#define En 512
#define Sn 512
#define RING 32
#define NBLK 256

typedef _Float16 f16;
typedef _Float16 half8 __attribute__((ext_vector_type(8)));
typedef float f32x4 __attribute__((ext_vector_type(4)));
typedef unsigned long long u64;
typedef u64 u64x2 __attribute__((ext_vector_type(2)));

// ============================================================================
// Round 14: dual-stream interleaved persistent kernel.
//   The batch recurrence is independent per row. Split batch into stream A
//   (rows 0..31) and stream B (rows 32..63). Each block alternates
//   A-phase / B-phase; arrivals posted at END of a phase, gates polled at
//   TOP of the next same-stream phase -> the other stream's full phase
//   (~2 us) elapses in between, so barrier+store-visibility latency is
//   hidden and polls succeed immediately.
//   - per-stream rings: 2 x 513 x 32768 f16 (64 KB/step) - same 67 MB total
//   - per-stream arrival lines: A at bytes [0,2K), B at [2K,4K), 16 x 128 B
//   - 16-row A-fragments: mt = wv&1, kq = wv>>1 (kc = kq*4..+3), 8 MFMA/wave
//   - cell on tid<128 (32 rows x 4 units), reduce over 8 kq waves
//   - targeted coherence unchanged: device-scope packed 8 B h stores,
//     plain ring loads (fresh addresses -> never stale), Wh in LDS,
//     c in registers (cregA/cregB), gx block-local
// Fallbacks: no-ring -> round-12 coop kernel (241 us/chunk proven);
// coop-fail -> launch-per-step; small ws -> fb.
// ============================================================================

__global__ __launch_bounds__(256) void wpack_kernel(
    const float* __restrict__ Whi_, const float* __restrict__ Whf_,
    const float* __restrict__ Whg_, const float* __restrict__ Who_,
    const float* __restrict__ Wxi_, const float* __restrict__ Wxf_,
    const float* __restrict__ Wxg_, const float* __restrict__ Wxo_,
    f16* __restrict__ wpHi, f16* __restrict__ wpLo)
{
    int t = blockIdx.x * 256 + threadIdx.x;   // 786432 = 256*48*64
    int lane = t & 63;
    int rest = t >> 6;
    int kc = rest % 48;
    int bb = rest / 48;
    int n = lane & 15, g = n >> 2, du = n & 3;
    int u = bb * 4 + du;
    int klo = (lane >> 4) << 3;
    const float* Wh = (g == 0 ? Whi_ : g == 1 ? Whf_ : g == 2 ? Whg_ : Who_);
    const float* Wx = (g == 0 ? Wxi_ : g == 1 ? Wxf_ : g == 2 ? Wxg_ : Wxo_);
    const float* src = (kc < 32) ? (Wh + (size_t)u * Hn + kc * 32 + klo)
                                 : (Wx + (size_t)u * En + (kc - 32) * 32 + klo);
    float4 v0 = ((const float4*)src)[0];
    float4 v1 = ((const float4*)src)[1];
    float w[8] = {v0.x, v0.y, v0.z, v0.w, v1.x, v1.y, v1.z, v1.w};
    #pragma unroll
    for (int j = 0; j < 8; ++j) {
        f16 hi = (f16)w[j];
        float lo = (w[j] - (float)hi) * 2048.0f;
        wpHi[(size_t)t * 8 + j] = hi;
        wpLo[(size_t)t * 8 + j] = (f16)lo;
    }
}

__global__ __launch_bounds__(256) void epack_kernel(
    const int* __restrict__ x, const float* __restrict__ emb,
    f16* __restrict__ eF)
{
    int t = blockIdx.x * 256 + threadIdx.x;   // 2097152 = 512*16*4*64
    int lane = t & 63;
    int q = t >> 6;
    int mt = q & 3; q >>= 2;
    int kc2 = q & 15;
    int s = q >> 4;
    int b = mt * 16 + (lane & 15);
    int tok = x[b * Sn + s];
    int k = kc2 * 32 + ((lane >> 4) << 3);
    const float* src = emb + (size_t)tok * En + k;
    float4 v0 = ((const float4*)src)[0];
    float4 v1 = ((const float4*)src)[1];
    f16* dst = eF + (size_t)t * 8;
    dst[0] = (f16)v0.x; dst[1] = (f16)v0.y; dst[2] = (f16)v0.z; dst[3] = (f16)v0.w;
    dst[4] = (f16)v1.x; dst[5] = (f16)v1.y; dst[6] = (f16)v1.z; dst[7] = (f16)v1.w;
}

// ---------------- fallback gx kernel (round-6 proven) ----------------
__global__ __launch_bounds__(256) void gx_chunk_kernel(
    const half8* __restrict__ eF,
    const half8* __restrict__ wpHi, const half8* __restrict__ wpLo,
    float* __restrict__ gx, int chunk)
{
    int lane = threadIdx.x & 63;
    int id = blockIdx.x * 4 + (threadIdx.x >> 6);
    int sc = id >> 8;            // 0..31
    int bb = id & 255;
    int s = chunk * RING + sc;

    const half8* eFs = eF + (size_t)s * 4096 + lane;
    const half8* bH = wpHi + ((size_t)(bb * 48 + 32)) * 64 + lane;
    const half8* bL = wpLo + ((size_t)(bb * 48 + 32)) * 64 + lane;

    f32x4 aH[4], aL[4];
    #pragma unroll
    for (int mt = 0; mt < 4; ++mt) { aH[mt] = (f32x4)0.0f; aL[mt] = (f32x4)0.0f; }

    for (int kcx = 0; kcx < 16; ++kcx) {
        half8 bh = bH[(size_t)kcx * 64];
        half8 bl = bL[(size_t)kcx * 64];
        #pragma unroll
        for (int mt = 0; mt < 4; ++mt) {
            half8 a = eFs[(size_t)((kcx * 4 + mt) * 64)];
            aH[mt] = __builtin_amdgcn_mfma_f32_16x16x32_f16(a, bh, aH[mt], 0, 0, 0);
            aL[mt] = __builtin_amdgcn_mfma_f32_16x16x32_f16(a, bl, aL[mt], 0, 0, 0);
        }
    }

    int n = lane & 15, g = n >> 2, du = n & 3;
    int col = (g << 10) + bb * 4 + du;
    float* g0 = gx + (size_t)sc * (Bn * 4096) + col;
    #pragma unroll
    for (int mt = 0; mt < 4; ++mt) {
        #pragma unroll
        for (int r = 0; r < 4; ++r) {
            int b = mt * 16 + ((lane >> 4) << 2) + r;
            g0[(size_t)b * 4096] = aH[mt][r] + aL[mt][r] * (1.0f / 2048.0f);
        }
    }
}

// ---------------- fallback per-step kernel (round-6 proven) ----------------
template<bool USE_GX>
__global__ __launch_bounds__(1024) void step_kernel(
    const f16* __restrict__ hFin, f16* __restrict__ hFout,
    const half8* __restrict__ eF,
    const half8* __restrict__ wpHi, const half8* __restrict__ wpLo,
    const float* __restrict__ gx,
    const float* __restrict__ bi, const float* __restrict__ bf,
    const float* __restrict__ bg, const float* __restrict__ bo,
    float* __restrict__ c, float* __restrict__ hFinal, int s)
{
    __shared__ float preW[16][256];       // 16 KB

    const int tid  = threadIdx.x;
    const int lane = tid & 63;
    const int wv   = tid >> 6;
    const int mt   = wv & 3;
    const int kq   = wv >> 2;
    const int bb   = blockIdx.x;

    const half8* hin = (const half8*)hFin + lane;
    const half8* bHb = wpHi + (size_t)(bb * 48) * 64 + lane;
    const half8* bLb = wpLo + (size_t)(bb * 48) * 64 + lane;

    f32x4 accH = {0.f, 0.f, 0.f, 0.f};
    f32x4 accL = {0.f, 0.f, 0.f, 0.f};

    if (USE_GX) {
        #pragma unroll
        for (int i = 0; i < 8; ++i) {
            int kc = kq * 8 + i;
            half8 a  = hin[(size_t)((kc * 4 + mt) * 64)];
            half8 bh = bHb[(size_t)kc * 64];
            half8 bl = bLb[(size_t)kc * 64];
            accH = __builtin_amdgcn_mfma_f32_16x16x32_f16(a, bh, accH, 0, 0, 0);
            accL = __builtin_amdgcn_mfma_f32_16x16x32_f16(a, bl, accL, 0, 0, 0);
        }
    } else {
        const half8* eFs = eF + (size_t)s * 4096 + lane;
        #pragma unroll
        for (int i = 0; i < 12; ++i) {
            int kc = kq * 12 + i;
            half8 a = (kc < 32) ? hin[(size_t)((kc * 4 + mt) * 64)]
                                : eFs[(size_t)(((kc - 32) * 4 + mt) * 64)];
            half8 bh = bHb[(size_t)kc * 64];
            half8 bl = bLb[(size_t)kc * 64];
            accH = __builtin_amdgcn_mfma_f32_16x16x32_f16(a, bh, accH, 0, 0, 0);
            accL = __builtin_amdgcn_mfma_f32_16x16x32_f16(a, bl, accL, 0, 0, 0);
        }
    }

    f32x4 v;
    #pragma unroll
    for (int r = 0; r < 4; ++r) v[r] = accH[r] + accL[r] * (1.0f / 2048.0f);
    *(f32x4*)&preW[wv][lane * 4] = v;
    __syncthreads();

    if (tid < 256) {
        const int bcell = tid >> 2, ducell = tid & 3;
        const int colcell = bb * 4 + ducell;          // h-unit 0..1023
        const int msub = bcell & 15, mtp = bcell >> 4;
        const int base_i = ((msub >> 2) * 16) * 4 + (msub & 3);
        float sg_[4];
        #pragma unroll
        for (int g = 0; g < 4; ++g) {
            int idx = base_i + (g * 4 + ducell) * 4;
            sg_[g] = preW[0 * 4 + mtp][idx] + preW[1 * 4 + mtp][idx]
                   + preW[2 * 4 + mtp][idx] + preW[3 * 4 + mtp][idx];
        }
        float si = sg_[0] + bi[colcell];
        float sf = sg_[1] + bf[colcell];
        float sg = sg_[2] + bg[colcell];
        float so = sg_[3] + bo[colcell];
        if (USE_GX) {
            const float* gr = gx + ((size_t)(s & (RING - 1)) * Bn + bcell) * 4096;
            si += gr[colcell];        sf += gr[1024 + colcell];
            sg += gr[2048 + colcell]; so += gr[3072 + colcell];
        }
        float it = 1.f / (1.f + expf(-si));
        float ft = 1.f / (1.f + expf(-sf));
        float gt = tanhf(sg);
        float ot = 1.f / (1.f + expf(-so));
        int gi = bcell * Hn + colcell;
        float cn = ft * c[gi] + it * gt;
        c[gi] = cn;
        float hn = ot * tanhf(cn);
        int kch = colcell >> 5, dk = colcell & 31;
        int lp  = ((dk >> 3) << 4) | (bcell & 15);
        int mtp2 = bcell >> 4;
        hFout[((size_t)((kch * 4 + mtp2) * 64 + lp)) * 8 + (dk & 7)] = (f16)hn;
        if (s == Sn - 1) hFinal[gi] = hn;
    }
}

// ---------------- fallback coop kernel (round-12 proven, 241 us/chunk) -------
// double-buffer hF, device-scope loads, flat 16-line barrier, wave-0 poll.
__global__ __launch_bounds__(1024) void steps_chunk_coop(
    f16* __restrict__ hF,
    const half8* __restrict__ eF,
    const half8* __restrict__ wpHi, const half8* __restrict__ wpLo,
    float* __restrict__ gx,
    const float* __restrict__ bi, const float* __restrict__ bf,
    const float* __restrict__ bg, const float* __restrict__ bo,
    float* __restrict__ c, float* __restrict__ hFinal,
    unsigned* __restrict__ cntArr, int chunk)
{
    __shared__ alignas(16) f16 wHs[32 * 512];
    __shared__ alignas(16) f16 wLs[32 * 512];
    __shared__ float preW[16][256];

    const int tid  = threadIdx.x;
    const int lane = tid & 63;
    const int wv   = tid >> 6;
    const int mt   = wv & 3;
    const int kq   = wv >> 2;
    const int bb   = blockIdx.x;

    {
        const half8* srcH = wpHi + (size_t)(bb * 48) * 64;
        const half8* srcL = wpLo + (size_t)(bb * 48) * 64;
        half8* dH = (half8*)wHs;
        half8* dL = (half8*)wLs;
        #pragma unroll
        for (int i = 0; i < 2; ++i) {
            dH[tid + i * 1024] = srcH[tid + i * 1024];
            dL[tid + i * 1024] = srcL[tid + i * 1024];
        }
    }

    {
        const half8* bH = wpHi + ((size_t)(bb * 48 + 32)) * 64 + lane;
        const half8* bL = wpLo + ((size_t)(bb * 48 + 32)) * 64 + lane;
        #pragma unroll
        for (int t2 = 0; t2 < 2; ++t2) {
            int sc = wv * 2 + t2;
            int s = chunk * RING + sc;
            const half8* eFs = eF + (size_t)s * 4096 + lane;
            f32x4 aH[4], aL[4];
            #pragma unroll
            for (int m2 = 0; m2 < 4; ++m2) { aH[m2] = (f32x4)0.0f; aL[m2] = (f32x4)0.0f; }
            for (int kcx = 0; kcx < 16; ++kcx) {
                half8 bh = bH[(size_t)kcx * 64];
                half8 bl = bL[(size_t)kcx * 64];
                #pragma unroll
                for (int m2 = 0; m2 < 4; ++m2) {
                    half8 a = eFs[(size_t)((kcx * 4 + m2) * 64)];
                    aH[m2] = __builtin_amdgcn_mfma_f32_16x16x32_f16(a, bh, aH[m2], 0, 0, 0);
                    aL[m2] = __builtin_amdgcn_mfma_f32_16x16x32_f16(a, bl, aL[m2], 0, 0, 0);
                }
            }
            int n = lane & 15, g = n >> 2, du = n & 3;
            int col = (g << 10) + bb * 4 + du;
            float* g0 = gx + (size_t)sc * (Bn * 4096) + col;
            #pragma unroll
            for (int m2 = 0; m2 < 4; ++m2) {
                #pragma unroll
                for (int r = 0; r < 4; ++r) {
                    int b = m2 * 16 + ((lane >> 4) << 2) + r;
                    g0[(size_t)b * 4096] = aH[m2][r] + aL[m2][r] * (1.0f / 2048.0f);
                }
            }
        }
    }

    float creg = 0.f, bi_r = 0.f, bf_r = 0.f, bg_r = 0.f, bo_r = 0.f;
    int bcell = 0, ducell = 0, colcell = 0, gi = 0, mtp = 0, base_i = 0;
    int kch = 0, dk = 0, lp = 0;
    if (tid < 256) {
        bcell = tid >> 2; ducell = tid & 3;
        colcell = bb * 4 + ducell;
        gi = bcell * Hn + colcell;
        int msub = bcell & 15; mtp = bcell >> 4;
        base_i = ((msub >> 2) * 16) * 4 + (msub & 3);
        creg = c[gi];
        bi_r = bi[colcell]; bf_r = bf[colcell];
        bg_r = bg[colcell]; bo_r = bo[colcell];
        kch = colcell >> 5; dk = colcell & 31;
        lp  = ((dk >> 3) << 4) | (bcell & 15);
    }

    __syncthreads();

    const half8* wHl = (const half8*)wHs + lane;
    const half8* wLl = (const half8*)wLs + lane;

    float gxi = 0.f, gxf = 0.f, gxg = 0.f, gxo = 0.f;
    if (tid < 256) {
        const float* gr = gx + ((size_t)0 * Bn + bcell) * 4096 + colcell;
        gxi = gr[0];    gxf = gr[1024];
        gxg = gr[2048]; gxo = gr[3072];
    }

    #pragma unroll 1
    for (int sc = 0; sc < RING; ++sc) {
        const int s = chunk * RING + sc;
        const f16* hbase = hF + (size_t)(s & 1) * 65536;
        f16* hout = hF + (size_t)((s + 1) & 1) * 65536;

        half8 afr[8];
        #pragma unroll
        for (int i = 0; i < 8; ++i) {
            const int kc = kq * 8 + i;
            const u64* q = (const u64*)(hbase
                + ((size_t)((kc * 4 + mt) * 64 + lane)) * 8);
            u64x2 u;
            u.x = __hip_atomic_load(q, __ATOMIC_RELAXED, __HIP_MEMORY_SCOPE_AGENT);
            u.y = __hip_atomic_load(q + 1, __ATOMIC_RELAXED, __HIP_MEMORY_SCOPE_AGENT);
            afr[i] = __builtin_bit_cast(half8, u);
        }

        f32x4 accH = {0.f, 0.f, 0.f, 0.f};
        f32x4 accL = {0.f, 0.f, 0.f, 0.f};
        #pragma unroll
        for (int i = 0; i < 8; ++i) {
            const int kc = kq * 8 + i;
            half8 bh = wHl[(size_t)kc * 64];
            half8 bl = wLl[(size_t)kc * 64];
            accH = __builtin_amdgcn_mfma_f32_16x16x32_f16(afr[i], bh, accH, 0, 0, 0);
            accL = __builtin_amdgcn_mfma_f32_16x16x32_f16(afr[i], bl, accL, 0, 0, 0);
        }
        f32x4 v;
        #pragma unroll
        for (int r = 0; r < 4; ++r) v[r] = accH[r] + accL[r] * (1.0f / 2048.0f);
        *(f32x4*)&preW[wv][lane * 4] = v;
        __syncthreads();

        if (tid < 256) {
            float sg_[4];
            #pragma unroll
            for (int g = 0; g < 4; ++g) {
                int idx = base_i + (g * 4 + ducell) * 4;
                sg_[g] = preW[mtp][idx] + preW[4 + mtp][idx]
                       + preW[8 + mtp][idx] + preW[12 + mtp][idx];
            }
            float si = sg_[0] + bi_r + gxi;
            float sf = sg_[1] + bf_r + gxf;
            float sg = sg_[2] + bg_r + gxg;
            float so = sg_[3] + bo_r + gxo;
            float it = 1.f / (1.f + expf(-si));
            float ft = 1.f / (1.f + expf(-sf));
            float gt = tanhf(sg);
            float ot = 1.f / (1.f + expf(-so));
            float cn = ft * creg + it * gt;
            creg = cn;
            float hn = ot * tanhf(cn);
            union { f16 h; unsigned short u; } cv;
            cv.h = (f16)hn;
            unsigned v0 = cv.u;
            unsigned v1 = (unsigned)__shfl_down((int)v0, 1, 64);
            unsigned v2 = (unsigned)__shfl_down((int)v0, 2, 64);
            unsigned v3 = (unsigned)__shfl_down((int)v0, 3, 64);
            if (ducell == 0) {
                u64 pack = (u64)(v0 & 0xffffu) | ((u64)(v1 & 0xffffu) << 16)
                         | ((u64)(v2 & 0xffffu) << 32) | ((u64)(v3 & 0xffffu) << 48);
                u64* paddr = (u64*)(hout
                    + ((size_t)((kch * 4 + mtp) * 64 + lp)) * 8 + (dk & 7));
                __hip_atomic_store(paddr, pack, __ATOMIC_RELAXED,
                                   __HIP_MEMORY_SCOPE_AGENT);
            }
            if (s == Sn - 1) hFinal[gi] = hn;
        }

        if (sc < RING - 1) {
            asm volatile("s_waitcnt vmcnt(0)" ::: "memory");
            __syncthreads();
            if (tid == 0)
                __hip_atomic_fetch_add(cntArr + (((unsigned)bb & 15u) << 5), 1u,
                                       __ATOMIC_RELAXED, __HIP_MEMORY_SCOPE_AGENT);
            if (tid < 256) {
                const float* gr = gx + ((size_t)(sc + 1) * Bn + bcell) * 4096
                                + colcell;
                gxi = gr[0];    gxf = gr[1024];
                gxg = gr[2048]; gxo = gr[3072];
            }
            if (wv == 0) {
                const unsigned B = (unsigned)(chunk * (RING - 1) + sc);
                const unsigned need = 256u * (B + 1u);
                while (true) {
                    unsigned pv = __hip_atomic_load(
                        cntArr + (((unsigned)lane & 15u) << 5),
                        __ATOMIC_RELAXED, __HIP_MEMORY_SCOPE_AGENT);
                    pv += (unsigned)__shfl_xor((int)pv, 1, 64);
                    pv += (unsigned)__shfl_xor((int)pv, 2, 64);
                    pv += (unsigned)__shfl_xor((int)pv, 4, 64);
                    pv += (unsigned)__shfl_xor((int)pv, 8, 64);
                    if (pv >= need) break;
                    __builtin_amdgcn_s_sleep(1);
                }
            }
            __syncthreads();
        }
    }

    if (tid < 256) c[gi] = creg;
}

// ---------------- dual-stream interleaved persistent kernel ----------------
// hRing: stream A ring at [0, 513*32768), stream B at [513*32768, ...).
// Per step: 32768 f16 (64 KB). Frag: [(kc*2+mt)*64+lane]*8+j,
//   b_local = mt*16+(lane&15), k = kc*32+(lane>>4)*8+j, kc 0..31, mt 0..1.
// cnt: stream A lines at uint32 idx j*32 (j=0..15), stream B at 512 + j*32.
__global__ __launch_bounds__(1024) void steps_chunk_dual(
    f16* __restrict__ hRing,
    const half8* __restrict__ eF,
    const half8* __restrict__ wpHi, const half8* __restrict__ wpLo,
    float* __restrict__ gx,
    const float* __restrict__ bi, const float* __restrict__ bf,
    const float* __restrict__ bg, const float* __restrict__ bo,
    float* __restrict__ c, float* __restrict__ hFinal,
    unsigned* __restrict__ cntArr, int chunk)
{
    __shared__ alignas(16) f16 wHs[32 * 512];   // 32 KB
    __shared__ alignas(16) f16 wLs[32 * 512];   // 32 KB
    __shared__ float preW[16][256];             // 16 KB

    const int tid  = threadIdx.x;
    const int lane = tid & 63;
    const int wv   = tid >> 6;
    const int mt   = wv & 1;        // row-tile within 32-row half-batch
    const int kq   = wv >> 1;       // 0..7 -> kc = kq*4 .. kq*4+3
    const int bb   = blockIdx.x;

    // ---- stage this block's Wh weights into LDS ----
    {
        const half8* srcH = wpHi + (size_t)(bb * 48) * 64;
        const half8* srcL = wpLo + (size_t)(bb * 48) * 64;
        half8* dH = (half8*)wHs;
        half8* dL = (half8*)wLs;
        #pragma unroll
        for (int i = 0; i < 2; ++i) {
            dH[tid + i * 1024] = srcH[tid + i * 1024];
            dL[tid + i * 1024] = srcL[tid + i * 1024];
        }
    }

    // ---- gx prologue (full batch; unchanged layout) ----
    {
        const half8* bH = wpHi + ((size_t)(bb * 48 + 32)) * 64 + lane;
        const half8* bL = wpLo + ((size_t)(bb * 48 + 32)) * 64 + lane;
        #pragma unroll
        for (int t2 = 0; t2 < 2; ++t2) {
            int sc = wv * 2 + t2;
            int s = chunk * RING + sc;
            const half8* eFs = eF + (size_t)s * 4096 + lane;
            f32x4 aH[4], aL[4];
            #pragma unroll
            for (int m2 = 0; m2 < 4; ++m2) { aH[m2] = (f32x4)0.0f; aL[m2] = (f32x4)0.0f; }
            for (int kcx = 0; kcx < 16; ++kcx) {
                half8 bh = bH[(size_t)kcx * 64];
                half8 bl = bL[(size_t)kcx * 64];
                #pragma unroll
                for (int m2 = 0; m2 < 4; ++m2) {
                    half8 a = eFs[(size_t)((kcx * 4 + m2) * 64)];
                    aH[m2] = __builtin_amdgcn_mfma_f32_16x16x32_f16(a, bh, aH[m2], 0, 0, 0);
                    aL[m2] = __builtin_amdgcn_mfma_f32_16x16x32_f16(a, bl, aL[m2], 0, 0, 0);
                }
            }
            int n = lane & 15, g = n >> 2, du = n & 3;
            int col = (g << 10) + bb * 4 + du;
            float* g0 = gx + (size_t)sc * (Bn * 4096) + col;
            #pragma unroll
            for (int m2 = 0; m2 < 4; ++m2) {
                #pragma unroll
                for (int r = 0; r < 4; ++r) {
                    int b = m2 * 16 + ((lane >> 4) << 2) + r;
                    g0[(size_t)b * 4096] = aH[m2][r] + aL[m2][r] * (1.0f / 2048.0f);
                }
            }
        }
    }

    // ---- per-cell persistent state (tid<128: 32 rows x 4 units) ----
    float cregA = 0.f, cregB = 0.f;
    float bi_r = 0.f, bf_r = 0.f, bg_r = 0.f, bo_r = 0.f;
    int bcell = 0, ducell = 0, colcell = 0, giA = 0, giB = 0;
    int mtp = 0, base_i = 0, kch = 0, dk = 0, lp = 0;
    if (tid < 128) {
        bcell = tid >> 2; ducell = tid & 3;          // bcell 0..31
        colcell = bb * 4 + ducell;
        giA = bcell * Hn + colcell;
        giB = (bcell + 32) * Hn + colcell;
        int msub = bcell & 15; mtp = bcell >> 4;     // mtp 0..1
        base_i = ((msub >> 2) * 16) * 4 + (msub & 3);
        cregA = c[giA]; cregB = c[giB];
        bi_r = bi[colcell]; bf_r = bf[colcell];
        bg_r = bg[colcell]; bo_r = bo[colcell];
        kch = colcell >> 5; dk = colcell & 31;
        lp  = ((dk >> 3) << 4) | (bcell & 15);
    }

    __syncthreads();   // gx prologue + LDS staging complete

    const half8* wHl = (const half8*)wHs + lane;
    const half8* wLl = (const half8*)wLs + lane;

    #pragma unroll 1
    for (int sc = 0; sc < RING; ++sc) {
        const int s = chunk * RING + sc;
        #pragma unroll
        for (int sg0 = 0; sg0 < 2; ++sg0) {
            const f16* hbase = hRing + (size_t)sg0 * (513 * 32768)
                                     + (size_t)s * 32768;
            f16* hout = hRing + (size_t)sg0 * (513 * 32768)
                              + (size_t)(s + 1) * 32768;
            unsigned* lines = cntArr + sg0 * 512;

            // ---- gate (poll-late: other stream's phase ran since arrive) ----
            if (sc > 0) {
                if (wv == 0) {
                    const unsigned need =
                        256u * ((unsigned)chunk * (RING - 1) + (unsigned)sc);
                    while (true) {
                        unsigned pv = __hip_atomic_load(
                            lines + (((unsigned)lane & 15u) << 5),
                            __ATOMIC_RELAXED, __HIP_MEMORY_SCOPE_AGENT);
                        pv += (unsigned)__shfl_xor((int)pv, 1, 64);
                        pv += (unsigned)__shfl_xor((int)pv, 2, 64);
                        pv += (unsigned)__shfl_xor((int)pv, 4, 64);
                        pv += (unsigned)__shfl_xor((int)pv, 8, 64);
                        if (pv >= need) break;
                        __builtin_amdgcn_s_sleep(1);
                    }
                }
                __syncthreads();
            }

            // gx loads (block-local; latency hides under MFMA chain)
            float gxi = 0.f, gxf = 0.f, gxg = 0.f, gxo = 0.f;
            if (tid < 128) {
                const float* gr = gx + ((size_t)sc * Bn + sg0 * 32 + bcell) * 4096
                                + colcell;
                gxi = gr[0];    gxf = gr[1024];
                gxg = gr[2048]; gxo = gr[3072];
            }

            // h loads (plain: fresh ring address, L2-shared per XCD)
            half8 afr[4];
            #pragma unroll
            for (int i = 0; i < 4; ++i) {
                const int kc = kq * 4 + i;
                afr[i] = *(const half8*)(hbase
                    + ((size_t)((kc * 2 + mt) * 64 + lane)) * 8);
            }

            f32x4 accH = {0.f, 0.f, 0.f, 0.f};
            f32x4 accL = {0.f, 0.f, 0.f, 0.f};
            #pragma unroll
            for (int i = 0; i < 4; ++i) {
                const int kc = kq * 4 + i;
                half8 bh = wHl[(size_t)kc * 64];
                half8 bl = wLl[(size_t)kc * 64];
                accH = __builtin_amdgcn_mfma_f32_16x16x32_f16(afr[i], bh, accH, 0, 0, 0);
                accL = __builtin_amdgcn_mfma_f32_16x16x32_f16(afr[i], bl, accL, 0, 0, 0);
            }
            f32x4 v;
            #pragma unroll
            for (int r = 0; r < 4; ++r) v[r] = accH[r] + accL[r] * (1.0f / 2048.0f);
            *(f32x4*)&preW[wv][lane * 4] = v;
            __syncthreads();

            if (tid < 128) {
                float sg_[4];
                #pragma unroll
                for (int g = 0; g < 4; ++g) {
                    int idx = base_i + (g * 4 + ducell) * 4;
                    float acc = 0.f;
                    #pragma unroll
                    for (int q = 0; q < 8; ++q)
                        acc += preW[q * 2 + mtp][idx];
                    sg_[g] = acc;
                }
                float si = sg_[0] + bi_r + gxi;
                float sf = sg_[1] + bf_r + gxf;
                float sg = sg_[2] + bg_r + gxg;
                float so = sg_[3] + bo_r + gxo;
                float it = 1.f / (1.f + expf(-si));
                float ft = 1.f / (1.f + expf(-sf));
                float gt = tanhf(sg);
                float ot = 1.f / (1.f + expf(-so));
                float cprev = sg0 ? cregB : cregA;
                float cn = ft * cprev + it * gt;
                if (sg0) cregB = cn; else cregA = cn;
                float hn = ot * tanhf(cn);
                // pack 4 f16 (ducell 0..3 adjacent lanes) -> one 8 B store
                union { f16 h; unsigned short u; } cv;
                cv.h = (f16)hn;
                unsigned v0 = cv.u;
                unsigned v1 = (unsigned)__shfl_down((int)v0, 1, 64);
                unsigned v2 = (unsigned)__shfl_down((int)v0, 2, 64);
                unsigned v3 = (unsigned)__shfl_down((int)v0, 3, 64);
                if (ducell == 0) {
                    u64 pack = (u64)(v0 & 0xffffu) | ((u64)(v1 & 0xffffu) << 16)
                             | ((u64)(v2 & 0xffffu) << 32)
                             | ((u64)(v3 & 0xffffu) << 48);
                    u64* paddr = (u64*)(hout
                        + ((size_t)((kch * 2 + mtp) * 64 + lp)) * 8 + (dk & 7));
                    __hip_atomic_store(paddr, pack, __ATOMIC_RELAXED,
                                       __HIP_MEMORY_SCOPE_AGENT);
                }
                if (s == Sn - 1) hFinal[sg0 ? giB : giA] = hn;
            }

            // ---- arrive (early; polled late next same-stream phase) ----
            if (sc < RING - 1) {
                asm volatile("s_waitcnt vmcnt(0)" ::: "memory");
                __syncthreads();
                if (tid == 0)
                    __hip_atomic_fetch_add(lines + (((unsigned)bb & 15u) << 5),
                                           1u, __ATOMIC_RELAXED,
                                           __HIP_MEMORY_SCOPE_AGENT);
            }
        }
    }

    if (tid < 128) { c[giA] = cregA; c[giB] = cregB; }
}

// ---- tail ----
__global__ __launch_bounds__(256) void copy_hc(
    const float* __restrict__ h, const float* __restrict__ c,
    float* __restrict__ out)
{
    int i = blockIdx.x * 256 + threadIdx.x;
    out[128 + i] = h[i];
    out[128 + Bn * Hn + i] = c[i];
}

__global__ __launch_bounds__(64) void classifier(
    const float* __restrict__ h, const float* __restrict__ Vw,
    const float* __restrict__ Vb, float* __restrict__ out)
{
    int bid = blockIdx.x;
    int b = bid >> 1, n = bid & 1;
    int lane = threadIdx.x;
    float sum = 0.f;
    for (int k = lane; k < Hn; k += 64)
        sum += h[b * Hn + k] * Vw[n * Hn + k];
    #pragma unroll
    for (int off = 32; off > 0; off >>= 1)
        sum += __shfl_down(sum, off, 64);
    if (lane == 0)
        out[b * 2 + n] = sum + Vb[n];
}

// ======================= fallback (round-1 proven path) =======================

#define KT 128
#define KTP 132

__global__ __launch_bounds__(256) void lstm_step_fb(
    const int* __restrict__ x, const float* __restrict__ emb,
    const float* __restrict__ Wxi, const float* __restrict__ Wxf,
    const float* __restrict__ Wxg, const float* __restrict__ Wxo,
    const float* __restrict__ bi, const float* __restrict__ bf,
    const float* __restrict__ bg, const float* __restrict__ bo,
    const float* __restrict__ Whi, const float* __restrict__ Whf,
    const float* __restrict__ Whg, const float* __restrict__ Who,
    const float* __restrict__ h_in, const float* __restrict__ c_in,
    float* __restrict__ h_out, float* __restrict__ c_out, int s)
{
    __shared__ float sh[Bn][KTP];
    __shared__ float sw[16][KTP];
    const int tid = threadIdx.x;
    const int b = tid >> 2, j = tid & 3;
    const int cb = blockIdx.x * 4, col = cb + j;
    float acc0 = 0.f, acc1 = 0.f, acc2 = 0.f, acc3 = 0.f;

    for (int k0 = 0; k0 < En; k0 += KT) {
        for (int i = tid; i < Bn * (KT / 4); i += 256) {
            int bl = i >> 5, k4 = (i & 31) << 2;
            int tok = x[bl * Sn + s];
            *reinterpret_cast<float4*>(&sh[bl][k4]) =
                *reinterpret_cast<const float4*>(&emb[(size_t)tok * En + k0 + k4]);
        }
        for (int i = tid; i < 16 * (KT / 4); i += 256) {
            int r = i >> 5, k4 = (i & 31) << 2;
            const float* Wg = (r < 8) ? ((r < 4) ? Wxi : Wxf)
                                      : ((r < 12) ? Wxg : Wxo);
            *reinterpret_cast<float4*>(&sw[r][k4]) =
                *reinterpret_cast<const float4*>(&Wg[(size_t)(cb + (r & 3)) * En + k0 + k4]);
        }
        __syncthreads();
        #pragma unroll 8
        for (int k = 0; k < KT; k += 4) {
            float4 hv = *reinterpret_cast<const float4*>(&sh[b][k]);
            float4 w0 = *reinterpret_cast<const float4*>(&sw[j][k]);
            float4 w1 = *reinterpret_cast<const float4*>(&sw[4 + j][k]);
            float4 w2 = *reinterpret_cast<const float4*>(&sw[8 + j][k]);
            float4 w3 = *reinterpret_cast<const float4*>(&sw[12 + j][k]);
            acc0 += hv.x*w0.x + hv.y*w0.y + hv.z*w0.z + hv.w*w0.w;
            acc1 += hv.x*w1.x + hv.y*w1.y + hv.z*w1.z + hv.w*w1.w;
            acc2 += hv.x*w2.x + hv.y*w2.y + hv.z*w2.z + hv.w*w2.w;
            acc3 += hv.x*w3.x + hv.y*w3.y + hv.z*w3.z + hv.w*w3.w;
        }
        __syncthreads();
    }
    for (int k0 = 0; k0 < Hn; k0 += KT) {
        for (int i = tid; i < Bn * (KT / 4); i += 256) {
            int bl = i >> 5, k4 = (i & 31) << 2;
            *reinterpret_cast<float4*>(&sh[bl][k4]) =
                *reinterpret_cast<const float4*>(&h_in[(size_t)bl * Hn + k0 + k4]);
        }
        for (int i = tid; i < 16 * (KT / 4); i += 256) {
            int r = i >> 5, k4 = (i & 31) << 2;
            const float* Wg = (r < 8) ? ((r < 4) ? Whi : Whf)
                                      : ((r < 12) ? Whg : Who);
            *reinterpret_cast<float4*>(&sw[r][k4]) =
                *reinterpret_cast<const float4*>(&Wg[(size_t)(cb + (r & 3)) * Hn + k0 + k4]);
        }
        __syncthreads();
        #pragma unroll 8
        for (int k = 0; k < KT; k += 4) {
            float4 hv = *reinterpret_cast<const float4*>(&sh[b][k]);
            float4 w0 = *reinterpret_cast<const float4*>(&sw[j][k]);
            float4 w1 = *reinterpret_cast<const float4*>(&sw[4 + j][k]);
            float4 w2 = *reinterpret_cast<const float4*>(&sw[8 + j][k]);
            float4 w3 = *reinterpret_cast<const float4*>(&sw[12 + j][k]);
            acc0 += hv.x*w0.x + hv.y*w0.y + hv.z*w0.z + hv.w*w0.w;
            acc1 += hv.x*w1.x + hv.y*w1.y + hv.z*w1.z + hv.w*w1.w;
            acc2 += hv.x*w2.x + hv.y*w2.y + hv.z*w2.z + hv.w*w2.w;
            acc3 += hv.x*w3.x + hv.y*w3.y + hv.z*w3.z + hv.w*w3.w;
        }
        __syncthreads();
    }
    acc0 += bi[col]; acc1 += bf[col]; acc2 += bg[col]; acc3 += bo[col];
    float it = 1.f / (1.f + expf(-acc0));
    float ft = 1.f / (1.f + expf(-acc1));
    float gt = tanhf(acc2);
    float ot = 1.f / (1.f + expf(-acc3));
    float cn = ft * c_in[b * Hn + col] + it * gt;
    c_out[b * Hn + col] = cn;
    h_out[b * Hn + col] = ot * tanhf(cn);
}

// ======================= launcher =======================

extern "C" void kernel_launch(void* const* d_in, const int* in_sizes, int n_in,
                              void* d_out, int out_size, void* d_ws, size_t ws_size,
                              hipStream_t stream) {
    const int*   x   = (const int*)  d_in[0];
    const float* emb = (const float*)d_in[1];
    const float* Wxi = (const float*)d_in[2];
    const float* bi  = (const float*)d_in[3];
    const float* Whi = (const float*)d_in[4];
    const float* Wxf = (const float*)d_in[5];
    const float* bf  = (const float*)d_in[6];
    const float* Whf = (const float*)d_in[7];
    const float* Wxg = (const float*)d_in[8];
    const float* bg  = (const float*)d_in[9];
    const float* Whg = (const float*)d_in[10];
    const float* Wxo = (const float*)d_in[11];
    const float* bo  = (const float*)d_in[12];
    const float* Who = (const float*)d_in[13];
    const float* Vw  = (const float*)d_in[14];
    const float* Vb  = (const float*)d_in[15];
    float* out = (float*)d_out;

    // ws: [hF 256K][c 256K][h 256K][eF 32M][wpHi 12M][wpLo 12M][gx 32M]
    //     [cnt 4K][hRing 67.2M = 2 streams x 513 x 64 KB]
    const size_t szHF   = (size_t)2 * 65536 * sizeof(f16);              // 256 KB
    const size_t szC    = (size_t)Bn * Hn * sizeof(float);              // 256 KB
    const size_t szEF   = (size_t)Sn * 16 * 4 * 64 * 8 * sizeof(f16);   // 32 MB
    const size_t szWp   = (size_t)256 * 48 * 64 * 8 * sizeof(f16);      // 12 MB
    const size_t szGx   = (size_t)RING * Bn * 4096 * sizeof(float);     // 32 MB
    const size_t szRing = (size_t)(Sn + 1) * 65536 * sizeof(f16);       // 67.2 MB
    const size_t need_mid  = szHF + 2 * szC + szEF + 2 * szWp;
    const size_t need_gx   = need_mid + szGx;
    const size_t need_coop = need_gx + 4096;
    const size_t need_ring = need_coop + szRing;

    if (ws_size >= need_mid) {
        const bool haveGx   = (ws_size >= need_gx);
        const bool haveCoop = (ws_size >= need_coop);
        const bool haveRing = (ws_size >= need_ring);
        char* base = (char*)d_ws;
        f16*   hF   = (f16*)base;   base += szHF;
        float* c    = (float*)base; base += szC;
        float* h    = (float*)base; base += szC;
        f16*   eF   = (f16*)base;   base += szEF;
        f16*   wpHi = (f16*)base;   base += szWp;
        f16*   wpLo = (f16*)base;   base += szWp;
        float* gx   = (float*)base; base += szGx;
        unsigned* cnt = (unsigned*)base; base += 4096;
        f16*   hRing = (f16*)base;

        hipMemsetAsync(d_ws, 0, szHF + szC, stream);   // hF both bufs + c
        if (haveCoop) hipMemsetAsync(cnt, 0, 4096, stream);
        if (haveRing) {
            hipMemsetAsync(hRing, 0, 32768 * sizeof(f16), stream);  // A step 0
            hipMemsetAsync(hRing + (size_t)513 * 32768, 0,
                           32768 * sizeof(f16), stream);            // B step 0
        }
        wpack_kernel<<<dim3(3072), dim3(256), 0, stream>>>(
            Whi, Whf, Whg, Who, Wxi, Wxf, Wxg, Wxo, wpHi, wpLo);
        epack_kernel<<<dim3(8192), dim3(256), 0, stream>>>(x, emb, eF);

        if (haveGx) {
            bool coop = haveCoop;
            for (int chunk = 0; chunk < Sn / RING; ++chunk) {
                if (coop) {
                    f16* hFp = hF;
                    f16* hRp = hRing;
                    const half8* eF8   = (const half8*)eF;
                    const half8* wpHi8 = (const half8*)wpHi;
                    const half8* wpLo8 = (const half8*)wpLo;
                    float* gxp = gx;
                    const float* bip = bi; const float* bfp = bf;
                    const float* bgp = bg; const float* bop = bo;
                    float* cp = c; float* hp = h;
                    unsigned* cntp = cnt;
                    int ci = chunk;
                    hipError_t e;
                    if (haveRing) {
                        void* args[] = { &hRp, &eF8, &wpHi8, &wpLo8, &gxp,
                                         &bip, &bfp, &bgp, &bop, &cp, &hp,
                                         &cntp, &ci };
                        e = hipLaunchCooperativeKernel(
                            (const void*)steps_chunk_dual, dim3(NBLK),
                            dim3(1024), args, 0, stream);
                    } else {
                        void* args[] = { &hFp, &eF8, &wpHi8, &wpLo8, &gxp,
                                         &bip, &bfp, &bgp, &bop, &cp, &hp,
                                         &cntp, &ci };
                        e = hipLaunchCooperativeKernel(
                            (const void*)steps_chunk_coop, dim3(NBLK),
                            dim3(1024), args, 0, stream);
                    }
                    if (e != hipSuccess) { coop = false; (void)hipGetLastError(); }
                }
                if (!coop) {
                    gx_chunk_kernel<<<dim3(2048), dim3(256), 0, stream>>>(
                        (const half8*)eF, (const half8*)wpHi, (const half8*)wpLo,
                        gx, chunk);
                    for (int sc = 0; sc < RING; ++sc) {
                        int s = chunk * RING + sc;
                        const f16* hin  = hF + (size_t)(s & 1) * 65536;
                        f16*       hout = hF + (size_t)((s + 1) & 1) * 65536;
                        step_kernel<true><<<dim3(256), dim3(1024), 0, stream>>>(
                            hin, hout, (const half8*)eF,
                            (const half8*)wpHi, (const half8*)wpLo,
                            gx, bi, bf, bg, bo, c, h, s);
                    }
                }
            }
        } else {
            for (int s = 0; s < Sn; ++s) {
                const f16* hin  = hF + (size_t)(s & 1) * 65536;
                f16*       hout = hF + (size_t)((s + 1) & 1) * 65536;
                step_kernel<false><<<dim3(256), dim3(1024), 0, stream>>>(
                    hin, hout, (const half8*)eF,
                    (const half8*)wpHi, (const half8*)wpLo,
                    (const float*)nullptr, bi, bf, bg, bo, c, h, s);
            }
        }
        copy_hc<<<dim3(Bn * Hn / 256), dim3(256), 0, stream>>>(h, c, out);
        classifier<<<dim3(Bn * 2), dim3(64), 0, stream>>>(h, Vw, Vb, out);
    } else {
        float* hA = (float*)d_ws;
        float* cA = hA + Bn * Hn;
        float* hB = cA + Bn * Hn;
        float* cB = hB + Bn * Hn;
        hipMemsetAsync(d_ws, 0, (size_t)2 * Bn * Hn * sizeof(float), stream);
        for (int s = 0; s < Sn; ++s) {
            const float* hi = (s & 1) ? hB : hA;
            const float* ci = (s & 1) ? cB : cA;
            float* ho = (s & 1) ? hA : hB;
            float* co = (s & 1) ? cA : cB;
            lstm_step_fb<<<dim3(Hn / 4), dim3(256), 0, stream>>>(
                x, emb, Wxi, Wxf, Wxg, Wxo, bi, bf, bg, bo,
                Whi, Whf, Whg, Who, hi, ci, ho, co, s);
        }
        copy_hc<<<dim3(Bn * Hn / 256), dim3(256), 0, stream>>>(hA, cA, out);
        classifier<<<dim3(Bn * 2), dim3(64), 0, stream>>>(hA, Vw, Vb, out);
    }
}

// Round 9
// 4151.435 us; speedup vs baseline: 1.0240x; 1.0240x over previous
//
#include <hip/hip_runtime.h>
#include <math.h>

#define Bn 64
#define Hn 1024
#define En 512
#define Sn 512
#define RING 32
#define NBLK 256

typedef _Float16 f16;
typedef _Float16 half8 __attribute__((ext_vector_type(8)));
typedef float f32x4 __attribute__((ext_vector_type(4)));
typedef unsigned long long u64;
typedef u64 u64x2 __attribute__((ext_vector_type(2)));

// ============================================================================
// Round 15: round-13 kernel (best: 219 us/chunk, 3759 total) with ONE change:
//   EARLY PER-WAVE ARRIVAL. Only waves 0..3 (cell waves) issue h stores;
//   the old block-wide vmcnt(0)+syncthreads before the tid0 arrival just
//   delayed it by the 16-wave convergence time. Now each cell wave posts
//   its own arrival right after its OWN wave-level vmcnt(0) drain:
//     line = (bb&15) | (wv<<4)  -> 64 lines x 128 B, 16 RMWs/line
//   Poll: wave 0 loads all 64 lines (lane), 6x shfl_xor sum,
//   need = 1024*(B+1). One syncthreads (after poll) still protects preW.
//   R8's dual-stream interleave is reverted (phase-overhead doubling lost).
// Everything else identical to round 13:
//   - per-step h ring (fresh addresses -> plain loads, L2-shared per XCD)
//   - device-scope packed 8 B h stores; gx block-local; Wh in LDS;
//     c in registers; gx prefetch under the poll
// ============================================================================

__global__ __launch_bounds__(256) void wpack_kernel(
    const float* __restrict__ Whi_, const float* __restrict__ Whf_,
    const float* __restrict__ Whg_, const float* __restrict__ Who_,
    const float* __restrict__ Wxi_, const float* __restrict__ Wxf_,
    const float* __restrict__ Wxg_, const float* __restrict__ Wxo_,
    f16* __restrict__ wpHi, f16* __restrict__ wpLo)
{
    int t = blockIdx.x * 256 + threadIdx.x;   // 786432 = 256*48*64
    int lane = t & 63;
    int rest = t >> 6;
    int kc = rest % 48;
    int bb = rest / 48;
    int n = lane & 15, g = n >> 2, du = n & 3;
    int u = bb * 4 + du;
    int klo = (lane >> 4) << 3;
    const float* Wh = (g == 0 ? Whi_ : g == 1 ? Whf_ : g == 2 ? Whg_ : Who_);
    const float* Wx = (g == 0 ? Wxi_ : g == 1 ? Wxf_ : g == 2 ? Wxg_ : Wxo_);
    const float* src = (kc < 32) ? (Wh + (size_t)u * Hn + kc * 32 + klo)
                                 : (Wx + (size_t)u * En + (kc - 32) * 32 + klo);
    float4 v0 = ((const float4*)src)[0];
    float4 v1 = ((const float4*)src)[1];
    float w[8] = {v0.x, v0.y, v0.z, v0.w, v1.x, v1.y, v1.z, v1.w};
    #pragma unroll
    for (int j = 0; j < 8; ++j) {
        f16 hi = (f16)w[j];
        float lo = (w[j] - (float)hi) * 2048.0f;
        wpHi[(size_t)t * 8 + j] = hi;
        wpLo[(size_t)t * 8 + j] = (f16)lo;
    }
}

__global__ __launch_bounds__(256) void epack_kernel(
    const int* __restrict__ x, const float* __restrict__ emb,
    f16* __restrict__ eF)
{
    int t = blockIdx.x * 256 + threadIdx.x;   // 2097152 = 512*16*4*64
    int lane = t & 63;
    int q = t >> 6;
    int mt = q & 3; q >>= 2;
    int kc2 = q & 15;
    int s = q >> 4;
    int b = mt * 16 + (lane & 15);
    int tok = x[b * Sn + s];
    int k = kc2 * 32 + ((lane >> 4) << 3);
    const float* src = emb + (size_t)tok * En + k;
    float4 v0 = ((const float4*)src)[0];
    float4 v1 = ((const float4*)src)[1];
    f16* dst = eF + (size_t)t * 8;
    dst[0] = (f16)v0.x; dst[1] = (f16)v0.y; dst[2] = (f16)v0.z; dst[3] = (f16)v0.w;
    dst[4] = (f16)v1.x; dst[5] = (f16)v1.y; dst[6] = (f16)v1.z; dst[7] = (f16)v1.w;
}

// ---------------- fallback gx kernel (round-6 proven) ----------------
__global__ __launch_bounds__(256) void gx_chunk_kernel(
    const half8* __restrict__ eF,
    const half8* __restrict__ wpHi, const half8* __restrict__ wpLo,
    float* __restrict__ gx, int chunk)
{
    int lane = threadIdx.x & 63;
    int id = blockIdx.x * 4 + (threadIdx.x >> 6);
    int sc = id >> 8;            // 0..31
    int bb = id & 255;
    int s = chunk * RING + sc;

    const half8* eFs = eF + (size_t)s * 4096 + lane;
    const half8* bH = wpHi + ((size_t)(bb * 48 + 32)) * 64 + lane;
    const half8* bL = wpLo + ((size_t)(bb * 48 + 32)) * 64 + lane;

    f32x4 aH[4], aL[4];
    #pragma unroll
    for (int mt = 0; mt < 4; ++mt) { aH[mt] = (f32x4)0.0f; aL[mt] = (f32x4)0.0f; }

    for (int kcx = 0; kcx < 16; ++kcx) {
        half8 bh = bH[(size_t)kcx * 64];
        half8 bl = bL[(size_t)kcx * 64];
        #pragma unroll
        for (int mt = 0; mt < 4; ++mt) {
            half8 a = eFs[(size_t)((kcx * 4 + mt) * 64)];
            aH[mt] = __builtin_amdgcn_mfma_f32_16x16x32_f16(a, bh, aH[mt], 0, 0, 0);
            aL[mt] = __builtin_amdgcn_mfma_f32_16x16x32_f16(a, bl, aL[mt], 0, 0, 0);
        }
    }

    int n = lane & 15, g = n >> 2, du = n & 3;
    int col = (g << 10) + bb * 4 + du;
    float* g0 = gx + (size_t)sc * (Bn * 4096) + col;
    #pragma unroll
    for (int mt = 0; mt < 4; ++mt) {
        #pragma unroll
        for (int r = 0; r < 4; ++r) {
            int b = mt * 16 + ((lane >> 4) << 2) + r;
            g0[(size_t)b * 4096] = aH[mt][r] + aL[mt][r] * (1.0f / 2048.0f);
        }
    }
}

// ---------------- fallback per-step kernel (round-6 proven) ----------------
template<bool USE_GX>
__global__ __launch_bounds__(1024) void step_kernel(
    const f16* __restrict__ hFin, f16* __restrict__ hFout,
    const half8* __restrict__ eF,
    const half8* __restrict__ wpHi, const half8* __restrict__ wpLo,
    const float* __restrict__ gx,
    const float* __restrict__ bi, const float* __restrict__ bf,
    const float* __restrict__ bg, const float* __restrict__ bo,
    float* __restrict__ c, float* __restrict__ hFinal, int s)
{
    __shared__ float preW[16][256];       // 16 KB

    const int tid  = threadIdx.x;
    const int lane = tid & 63;
    const int wv   = tid >> 6;
    const int mt   = wv & 3;
    const int kq   = wv >> 2;
    const int bb   = blockIdx.x;

    const half8* hin = (const half8*)hFin + lane;
    const half8* bHb = wpHi + (size_t)(bb * 48) * 64 + lane;
    const half8* bLb = wpLo + (size_t)(bb * 48) * 64 + lane;

    f32x4 accH = {0.f, 0.f, 0.f, 0.f};
    f32x4 accL = {0.f, 0.f, 0.f, 0.f};

    if (USE_GX) {
        #pragma unroll
        for (int i = 0; i < 8; ++i) {
            int kc = kq * 8 + i;
            half8 a  = hin[(size_t)((kc * 4 + mt) * 64)];
            half8 bh = bHb[(size_t)kc * 64];
            half8 bl = bLb[(size_t)kc * 64];
            accH = __builtin_amdgcn_mfma_f32_16x16x32_f16(a, bh, accH, 0, 0, 0);
            accL = __builtin_amdgcn_mfma_f32_16x16x32_f16(a, bl, accL, 0, 0, 0);
        }
    } else {
        const half8* eFs = eF + (size_t)s * 4096 + lane;
        #pragma unroll
        for (int i = 0; i < 12; ++i) {
            int kc = kq * 12 + i;
            half8 a = (kc < 32) ? hin[(size_t)((kc * 4 + mt) * 64)]
                                : eFs[(size_t)(((kc - 32) * 4 + mt) * 64)];
            half8 bh = bHb[(size_t)kc * 64];
            half8 bl = bLb[(size_t)kc * 64];
            accH = __builtin_amdgcn_mfma_f32_16x16x32_f16(a, bh, accH, 0, 0, 0);
            accL = __builtin_amdgcn_mfma_f32_16x16x32_f16(a, bl, accL, 0, 0, 0);
        }
    }

    f32x4 v;
    #pragma unroll
    for (int r = 0; r < 4; ++r) v[r] = accH[r] + accL[r] * (1.0f / 2048.0f);
    *(f32x4*)&preW[wv][lane * 4] = v;
    __syncthreads();

    if (tid < 256) {
        const int bcell = tid >> 2, ducell = tid & 3;
        const int colcell = bb * 4 + ducell;          // h-unit 0..1023
        const int msub = bcell & 15, mtp = bcell >> 4;
        const int base_i = ((msub >> 2) * 16) * 4 + (msub & 3);
        float sg_[4];
        #pragma unroll
        for (int g = 0; g < 4; ++g) {
            int idx = base_i + (g * 4 + ducell) * 4;
            sg_[g] = preW[0 * 4 + mtp][idx] + preW[1 * 4 + mtp][idx]
                   + preW[2 * 4 + mtp][idx] + preW[3 * 4 + mtp][idx];
        }
        float si = sg_[0] + bi[colcell];
        float sf = sg_[1] + bf[colcell];
        float sg = sg_[2] + bg[colcell];
        float so = sg_[3] + bo[colcell];
        if (USE_GX) {
            const float* gr = gx + ((size_t)(s & (RING - 1)) * Bn + bcell) * 4096;
            si += gr[colcell];        sf += gr[1024 + colcell];
            sg += gr[2048 + colcell]; so += gr[3072 + colcell];
        }
        float it = 1.f / (1.f + expf(-si));
        float ft = 1.f / (1.f + expf(-sf));
        float gt = tanhf(sg);
        float ot = 1.f / (1.f + expf(-so));
        int gi = bcell * Hn + colcell;
        float cn = ft * c[gi] + it * gt;
        c[gi] = cn;
        float hn = ot * tanhf(cn);
        int kch = colcell >> 5, dk = colcell & 31;
        int lp  = ((dk >> 3) << 4) | (bcell & 15);
        int mtp2 = bcell >> 4;
        hFout[((size_t)((kch * 4 + mtp2) * 64 + lp)) * 8 + (dk & 7)] = (f16)hn;
        if (s == Sn - 1) hFinal[gi] = hn;
    }
}

// ---------------- per-chunk persistent cooperative kernel ----------------
// cnt layout (uint32 indices): arrival line j at j*32 (128 B apart, j=0..63).
// Cell wave wv of block bb arrives on line (bb&15)|(wv<<4) after draining
// its own stores (wave-level vmcnt). 16 RMWs/line per barrier.
// Poll: wave 0 loads all 64 lines (lane), 6x shfl_xor sum, need 1024*(B+1).
// RINGM: h buffers hRing[s] (fresh address per step, plain loads, L2-shared).
template<bool RINGM>
__global__ __launch_bounds__(1024) void steps_chunk_coop(
    f16* __restrict__ hF,                 // 2 x 65536 f16 (double buffer)
    f16* __restrict__ hRing,              // 513 x 65536 f16 (RINGM only)
    const half8* __restrict__ eF,
    const half8* __restrict__ wpHi, const half8* __restrict__ wpLo,
    float* __restrict__ gx,
    const float* __restrict__ bi, const float* __restrict__ bf,
    const float* __restrict__ bg, const float* __restrict__ bo,
    float* __restrict__ c, float* __restrict__ hFinal,
    unsigned* __restrict__ cntArr, int chunk)
{
    __shared__ alignas(16) f16 wHs[32 * 512];   // 32 KB  Wh hi, kc 0..31
    __shared__ alignas(16) f16 wLs[32 * 512];   // 32 KB  Wh lo
    __shared__ float preW[16][256];             // 16 KB

    const int tid  = threadIdx.x;
    const int lane = tid & 63;
    const int wv   = tid >> 6;
    const int mt   = wv & 3;
    const int kq   = wv >> 2;
    const int bb   = blockIdx.x;

    // ---- stage this block's Wh weights into LDS ----
    {
        const half8* srcH = wpHi + (size_t)(bb * 48) * 64;
        const half8* srcL = wpLo + (size_t)(bb * 48) * 64;
        half8* dH = (half8*)wHs;
        half8* dL = (half8*)wLs;
        #pragma unroll
        for (int i = 0; i < 2; ++i) {         // 2048 half8 per buffer
            dH[tid + i * 1024] = srcH[tid + i * 1024];
            dL[tid + i * 1024] = srcL[tid + i * 1024];
        }
    }

    // ---- gx prologue: wave wv computes sc = 2*wv, 2*wv+1 for this bb ----
    {
        const half8* bH = wpHi + ((size_t)(bb * 48 + 32)) * 64 + lane;
        const half8* bL = wpLo + ((size_t)(bb * 48 + 32)) * 64 + lane;
        #pragma unroll
        for (int t2 = 0; t2 < 2; ++t2) {
            int sc = wv * 2 + t2;
            int s = chunk * RING + sc;
            const half8* eFs = eF + (size_t)s * 4096 + lane;
            f32x4 aH[4], aL[4];
            #pragma unroll
            for (int m2 = 0; m2 < 4; ++m2) { aH[m2] = (f32x4)0.0f; aL[m2] = (f32x4)0.0f; }
            for (int kcx = 0; kcx < 16; ++kcx) {
                half8 bh = bH[(size_t)kcx * 64];
                half8 bl = bL[(size_t)kcx * 64];
                #pragma unroll
                for (int m2 = 0; m2 < 4; ++m2) {
                    half8 a = eFs[(size_t)((kcx * 4 + m2) * 64)];
                    aH[m2] = __builtin_amdgcn_mfma_f32_16x16x32_f16(a, bh, aH[m2], 0, 0, 0);
                    aL[m2] = __builtin_amdgcn_mfma_f32_16x16x32_f16(a, bl, aL[m2], 0, 0, 0);
                }
            }
            int n = lane & 15, g = n >> 2, du = n & 3;
            int col = (g << 10) + bb * 4 + du;
            float* g0 = gx + (size_t)sc * (Bn * 4096) + col;
            #pragma unroll
            for (int m2 = 0; m2 < 4; ++m2) {
                #pragma unroll
                for (int r = 0; r < 4; ++r) {
                    int b = m2 * 16 + ((lane >> 4) << 2) + r;
                    g0[(size_t)b * 4096] = aH[m2][r] + aL[m2][r] * (1.0f / 2048.0f);
                }
            }
        }
    }

    // ---- per-cell persistent state ----
    float creg = 0.f, bi_r = 0.f, bf_r = 0.f, bg_r = 0.f, bo_r = 0.f;
    int bcell = 0, ducell = 0, colcell = 0, gi = 0, mtp = 0, base_i = 0;
    int kch = 0, dk = 0, lp = 0;
    if (tid < 256) {
        bcell = tid >> 2; ducell = tid & 3;
        colcell = bb * 4 + ducell;
        gi = bcell * Hn + colcell;
        int msub = bcell & 15; mtp = bcell >> 4;
        base_i = ((msub >> 2) * 16) * 4 + (msub & 3);
        creg = c[gi];
        bi_r = bi[colcell]; bf_r = bf[colcell];
        bg_r = bg[colcell]; bo_r = bo[colcell];
        kch = colcell >> 5; dk = colcell & 31;
        lp  = ((dk >> 3) << 4) | (bcell & 15);
    }

    __syncthreads();   // gx prologue + LDS staging complete

    const half8* wHl = (const half8*)wHs + lane;
    const half8* wLl = (const half8*)wLs + lane;

    // gx for step 0 (prefetched; later steps prefetched under the poll)
    float gxi = 0.f, gxf = 0.f, gxg = 0.f, gxo = 0.f;
    if (tid < 256) {
        const float* gr = gx + ((size_t)0 * Bn + bcell) * 4096 + colcell;
        gxi = gr[0];    gxf = gr[1024];
        gxg = gr[2048]; gxo = gr[3072];
    }

    #pragma unroll 1
    for (int sc = 0; sc < RING; ++sc) {
        const int s = chunk * RING + sc;
        const f16* hbase = RINGM ? hRing + (size_t)s * 65536
                                 : hF + (size_t)(s & 1) * 65536;
        f16* hout = RINGM ? hRing + (size_t)(s + 1) * 65536
                          : hF + (size_t)((s + 1) & 1) * 65536;

        // hF fragment loads.
        //  RINGM: plain loads - address is fresh (never cached stale), so
        //  local L2 serves 31/32 blocks per XCD after the first fill.
        //  else: device-scope relaxed atomics (bypass stale L1/L2 -> MALL).
        half8 afr[8];
        #pragma unroll
        for (int i = 0; i < 8; ++i) {
            const int kc = kq * 8 + i;
            const f16* p = hbase + ((size_t)((kc * 4 + mt) * 64 + lane)) * 8;
            if (RINGM) {
                afr[i] = *(const half8*)p;
            } else {
                const u64* q = (const u64*)p;
                u64x2 u;
                u.x = __hip_atomic_load(q, __ATOMIC_RELAXED,
                                        __HIP_MEMORY_SCOPE_AGENT);
                u.y = __hip_atomic_load(q + 1, __ATOMIC_RELAXED,
                                        __HIP_MEMORY_SCOPE_AGENT);
                afr[i] = __builtin_bit_cast(half8, u);
            }
        }

        f32x4 accH = {0.f, 0.f, 0.f, 0.f};
        f32x4 accL = {0.f, 0.f, 0.f, 0.f};
        #pragma unroll
        for (int i = 0; i < 8; ++i) {
            const int kc = kq * 8 + i;
            half8 bh = wHl[(size_t)kc * 64];
            half8 bl = wLl[(size_t)kc * 64];
            accH = __builtin_amdgcn_mfma_f32_16x16x32_f16(afr[i], bh, accH, 0, 0, 0);
            accL = __builtin_amdgcn_mfma_f32_16x16x32_f16(afr[i], bl, accL, 0, 0, 0);
        }
        f32x4 v;
        #pragma unroll
        for (int r = 0; r < 4; ++r) v[r] = accH[r] + accL[r] * (1.0f / 2048.0f);
        *(f32x4*)&preW[wv][lane * 4] = v;
        __syncthreads();

        if (tid < 256) {
            float sg_[4];
            #pragma unroll
            for (int g = 0; g < 4; ++g) {
                int idx = base_i + (g * 4 + ducell) * 4;
                sg_[g] = preW[mtp][idx] + preW[4 + mtp][idx]
                       + preW[8 + mtp][idx] + preW[12 + mtp][idx];
            }
            float si = sg_[0] + bi_r + gxi;
            float sf = sg_[1] + bf_r + gxf;
            float sg = sg_[2] + bg_r + gxg;
            float so = sg_[3] + bo_r + gxo;
            float it = 1.f / (1.f + expf(-si));
            float ft = 1.f / (1.f + expf(-sf));
            float gt = tanhf(sg);
            float ot = 1.f / (1.f + expf(-so));
            float cn = ft * creg + it * gt;
            creg = cn;
            float hn = ot * tanhf(cn);
            // pack 4 f16 (ducell 0..3 = 4 adjacent lanes) -> one 8 B store
            union { f16 h; unsigned short u; } cv;
            cv.h = (f16)hn;
            unsigned v0 = cv.u;
            unsigned v1 = (unsigned)__shfl_down((int)v0, 1, 64);
            unsigned v2 = (unsigned)__shfl_down((int)v0, 2, 64);
            unsigned v3 = (unsigned)__shfl_down((int)v0, 3, 64);
            if (ducell == 0) {
                u64 pack = (u64)(v0 & 0xffffu) | ((u64)(v1 & 0xffffu) << 16)
                         | ((u64)(v2 & 0xffffu) << 32) | ((u64)(v3 & 0xffffu) << 48);
                u64* paddr = (u64*)(hout
                    + ((size_t)((kch * 4 + mtp) * 64 + lp)) * 8 + (dk & 7));
                __hip_atomic_store(paddr, pack, __ATOMIC_RELAXED,
                                   __HIP_MEMORY_SCOPE_AGENT);
            }
            if (s == Sn - 1) hFinal[gi] = hn;
        }

        // ---- early per-wave arrival + flat barrier (skip on last step) ----
        if (sc < RING - 1) {
            if (wv < 4) {
                // drain THIS wave's h stores, then post its arrival
                asm volatile("s_waitcnt vmcnt(0)" ::: "memory");
                if (lane == 0)
                    __hip_atomic_fetch_add(
                        cntArr + ((((unsigned)bb & 15u) | ((unsigned)wv << 4)) << 5),
                        1u, __ATOMIC_RELAXED, __HIP_MEMORY_SCOPE_AGENT);
            }
            // prefetch next step's gx while waiting
            if (tid < 256) {
                const float* gr = gx + ((size_t)(sc + 1) * Bn + bcell) * 4096
                                + colcell;
                gxi = gr[0];    gxf = gr[1024];
                gxg = gr[2048]; gxo = gr[3072];
            }
            if (wv == 0) {
                const unsigned B = (unsigned)(chunk * (RING - 1) + sc);
                const unsigned need = 1024u * (B + 1u);
                while (true) {
                    unsigned pv = __hip_atomic_load(
                        cntArr + ((unsigned)lane << 5),
                        __ATOMIC_RELAXED, __HIP_MEMORY_SCOPE_AGENT);
                    pv += (unsigned)__shfl_xor((int)pv, 1, 64);
                    pv += (unsigned)__shfl_xor((int)pv, 2, 64);
                    pv += (unsigned)__shfl_xor((int)pv, 4, 64);
                    pv += (unsigned)__shfl_xor((int)pv, 8, 64);
                    pv += (unsigned)__shfl_xor((int)pv, 16, 64);
                    pv += (unsigned)__shfl_xor((int)pv, 32, 64);
                    if (pv >= need) break;
                    __builtin_amdgcn_s_sleep(1);
                }
            }
            __syncthreads();
        }
    }

    if (tid < 256) c[gi] = creg;
}

// ---- tail ----
__global__ __launch_bounds__(256) void copy_hc(
    const float* __restrict__ h, const float* __restrict__ c,
    float* __restrict__ out)
{
    int i = blockIdx.x * 256 + threadIdx.x;
    out[128 + i] = h[i];
    out[128 + Bn * Hn + i] = c[i];
}

__global__ __launch_bounds__(64) void classifier(
    const float* __restrict__ h, const float* __restrict__ Vw,
    const float* __restrict__ Vb, float* __restrict__ out)
{
    int bid = blockIdx.x;
    int b = bid >> 1, n = bid & 1;
    int lane = threadIdx.x;
    float sum = 0.f;
    for (int k = lane; k < Hn; k += 64)
        sum += h[b * Hn + k] * Vw[n * Hn + k];
    #pragma unroll
    for (int off = 32; off > 0; off >>= 1)
        sum += __shfl_down(sum, off, 64);
    if (lane == 0)
        out[b * 2 + n] = sum + Vb[n];
}

// ======================= fallback (round-1 proven path) =======================

#define KT 128
#define KTP 132

__global__ __launch_bounds__(256) void lstm_step_fb(
    const int* __restrict__ x, const float* __restrict__ emb,
    const float* __restrict__ Wxi, const float* __restrict__ Wxf,
    const float* __restrict__ Wxg, const float* __restrict__ Wxo,
    const float* __restrict__ bi, const float* __restrict__ bf,
    const float* __restrict__ bg, const float* __restrict__ bo,
    const float* __restrict__ Whi, const float* __restrict__ Whf,
    const float* __restrict__ Whg, const float* __restrict__ Who,
    const float* __restrict__ h_in, const float* __restrict__ c_in,
    float* __restrict__ h_out, float* __restrict__ c_out, int s)
{
    __shared__ float sh[Bn][KTP];
    __shared__ float sw[16][KTP];
    const int tid = threadIdx.x;
    const int b = tid >> 2, j = tid & 3;
    const int cb = blockIdx.x * 4, col = cb + j;
    float acc0 = 0.f, acc1 = 0.f, acc2 = 0.f, acc3 = 0.f;

    for (int k0 = 0; k0 < En; k0 += KT) {
        for (int i = tid; i < Bn * (KT / 4); i += 256) {
            int bl = i >> 5, k4 = (i & 31) << 2;
            int tok = x[bl * Sn + s];
            *reinterpret_cast<float4*>(&sh[bl][k4]) =
                *reinterpret_cast<const float4*>(&emb[(size_t)tok * En + k0 + k4]);
        }
        for (int i = tid; i < 16 * (KT / 4); i += 256) {
            int r = i >> 5, k4 = (i & 31) << 2;
            const float* Wg = (r < 8) ? ((r < 4) ? Wxi : Wxf)
                                      : ((r < 12) ? Wxg : Wxo);
            *reinterpret_cast<float4*>(&sw[r][k4]) =
                *reinterpret_cast<const float4*>(&Wg[(size_t)(cb + (r & 3)) * En + k0 + k4]);
        }
        __syncthreads();
        #pragma unroll 8
        for (int k = 0; k < KT; k += 4) {
            float4 hv = *reinterpret_cast<const float4*>(&sh[b][k]);
            float4 w0 = *reinterpret_cast<const float4*>(&sw[j][k]);
            float4 w1 = *reinterpret_cast<const float4*>(&sw[4 + j][k]);
            float4 w2 = *reinterpret_cast<const float4*>(&sw[8 + j][k]);
            float4 w3 = *reinterpret_cast<const float4*>(&sw[12 + j][k]);
            acc0 += hv.x*w0.x + hv.y*w0.y + hv.z*w0.z + hv.w*w0.w;
            acc1 += hv.x*w1.x + hv.y*w1.y + hv.z*w1.z + hv.w*w1.w;
            acc2 += hv.x*w2.x + hv.y*w2.y + hv.z*w2.z + hv.w*w2.w;
            acc3 += hv.x*w3.x + hv.y*w3.y + hv.z*w3.z + hv.w*w3.w;
        }
        __syncthreads();
    }
    for (int k0 = 0; k0 < Hn; k0 += KT) {
        for (int i = tid; i < Bn * (KT / 4); i += 256) {
            int bl = i >> 5, k4 = (i & 31) << 2;
            *reinterpret_cast<float4*>(&sh[bl][k4]) =
                *reinterpret_cast<const float4*>(&h_in[(size_t)bl * Hn + k0 + k4]);
        }
        for (int i = tid; i < 16 * (KT / 4); i += 256) {
            int r = i >> 5, k4 = (i & 31) << 2;
            const float* Wg = (r < 8) ? ((r < 4) ? Whi : Whf)
                                      : ((r < 12) ? Whg : Who);
            *reinterpret_cast<float4*>(&sw[r][k4]) =
                *reinterpret_cast<const float4*>(&Wg[(size_t)(cb + (r & 3)) * Hn + k0 + k4]);
        }
        __syncthreads();
        #pragma unroll 8
        for (int k = 0; k < KT; k += 4) {
            float4 hv = *reinterpret_cast<const float4*>(&sh[b][k]);
            float4 w0 = *reinterpret_cast<const float4*>(&sw[j][k]);
            float4 w1 = *reinterpret_cast<const float4*>(&sw[4 + j][k]);
            float4 w2 = *reinterpret_cast<const float4*>(&sw[8 + j][k]);
            float4 w3 = *reinterpret_cast<const float4*>(&sw[12 + j][k]);
            acc0 += hv.x*w0.x + hv.y*w0.y + hv.z*w0.z + hv.w*w0.w;
            acc1 += hv.x*w1.x + hv.y*w1.y + hv.z*w1.z + hv.w*w1.w;
            acc2 += hv.x*w2.x + hv.y*w2.y + hv.z*w2.z + hv.w*w2.w;
            acc3 += hv.x*w3.x + hv.y*w3.y + hv.z*w3.z + hv.w*w3.w;
        }
        __syncthreads();
    }
    acc0 += bi[col]; acc1 += bf[col]; acc2 += bg[col]; acc3 += bo[col];
    float it = 1.f / (1.f + expf(-acc0));
    float ft = 1.f / (1.f + expf(-acc1));
    float gt = tanhf(acc2);
    float ot = 1.f / (1.f + expf(-acc3));
    float cn = ft * c_in[b * Hn + col] + it * gt;
    c_out[b * Hn + col] = cn;
    h_out[b * Hn + col] = ot * tanhf(cn);
}

// ======================= launcher =======================

extern "C" void kernel_launch(void* const* d_in, const int* in_sizes, int n_in,
                              void* d_out, int out_size, void* d_ws, size_t ws_size,
                              hipStream_t stream) {
    const int*   x   = (const int*)  d_in[0];
    const float* emb = (const float*)d_in[1];
    const float* Wxi = (const float*)d_in[2];
    const float* bi  = (const float*)d_in[3];
    const float* Whi = (const float*)d_in[4];
    const float* Wxf = (const float*)d_in[5];
    const float* bf  = (const float*)d_in[6];
    const float* Whf = (const float*)d_in[7];
    const float* Wxg = (const float*)d_in[8];
    const float* bg  = (const float*)d_in[9];
    const float* Whg = (const float*)d_in[10];
    const float* Wxo = (const float*)d_in[11];
    const float* bo  = (const float*)d_in[12];
    const float* Who = (const float*)d_in[13];
    const float* Vw  = (const float*)d_in[14];
    const float* Vb  = (const float*)d_in[15];
    float* out = (float*)d_out;

    // ws: [hF 256K][c 256K][h 256K][eF 32M][wpHi 12M][wpLo 12M][gx 32M]
    //     [cnt 16K][hRing 67.2M]
    const size_t szHF   = (size_t)2 * 65536 * sizeof(f16);              // 256 KB
    const size_t szC    = (size_t)Bn * Hn * sizeof(float);              // 256 KB
    const size_t szEF   = (size_t)Sn * 16 * 4 * 64 * 8 * sizeof(f16);   // 32 MB
    const size_t szWp   = (size_t)256 * 48 * 64 * 8 * sizeof(f16);      // 12 MB
    const size_t szGx   = (size_t)RING * Bn * 4096 * sizeof(float);     // 32 MB
    const size_t szCnt  = 16384;
    const size_t szRing = (size_t)(Sn + 1) * 65536 * sizeof(f16);       // 67.2 MB
    const size_t need_mid  = szHF + 2 * szC + szEF + 2 * szWp;
    const size_t need_gx   = need_mid + szGx;
    const size_t need_coop = need_gx + szCnt;
    const size_t need_ring = need_coop + szRing;

    if (ws_size >= need_mid) {
        const bool haveGx   = (ws_size >= need_gx);
        const bool haveCoop = (ws_size >= need_coop);
        const bool haveRing = (ws_size >= need_ring);
        char* base = (char*)d_ws;
        f16*   hF   = (f16*)base;   base += szHF;
        float* c    = (float*)base; base += szC;
        float* h    = (float*)base; base += szC;
        f16*   eF   = (f16*)base;   base += szEF;
        f16*   wpHi = (f16*)base;   base += szWp;
        f16*   wpLo = (f16*)base;   base += szWp;
        float* gx   = (float*)base; base += szGx;
        unsigned* cnt = (unsigned*)base; base += szCnt;
        f16*   hRing = (f16*)base;

        hipMemsetAsync(d_ws, 0, szHF + szC, stream);   // hF both bufs + c
        if (haveCoop) hipMemsetAsync(cnt, 0, szCnt, stream);  // arrival lines
        if (haveRing) hipMemsetAsync(hRing, 0, 65536 * sizeof(f16), stream);
        wpack_kernel<<<dim3(3072), dim3(256), 0, stream>>>(
            Whi, Whf, Whg, Who, Wxi, Wxf, Wxg, Wxo, wpHi, wpLo);
        epack_kernel<<<dim3(8192), dim3(256), 0, stream>>>(x, emb, eF);

        if (haveGx) {
            bool coop = haveCoop;
            for (int chunk = 0; chunk < Sn / RING; ++chunk) {
                if (coop) {
                    f16* hFp = hF;
                    f16* hRp = hRing;
                    const half8* eF8   = (const half8*)eF;
                    const half8* wpHi8 = (const half8*)wpHi;
                    const half8* wpLo8 = (const half8*)wpLo;
                    float* gxp = gx;
                    const float* bip = bi; const float* bfp = bf;
                    const float* bgp = bg; const float* bop = bo;
                    float* cp = c; float* hp = h;
                    unsigned* cntp = cnt;
                    int ci = chunk;
                    void* args[] = { &hFp, &hRp, &eF8, &wpHi8, &wpLo8, &gxp,
                                     &bip, &bfp, &bgp, &bop, &cp, &hp,
                                     &cntp, &ci };
                    const void* fn = haveRing
                        ? (const void*)steps_chunk_coop<true>
                        : (const void*)steps_chunk_coop<false>;
                    hipError_t e = hipLaunchCooperativeKernel(
                        fn, dim3(NBLK), dim3(1024), args, 0, stream);
                    if (e != hipSuccess) { coop = false; (void)hipGetLastError(); }
                }
                if (!coop) {
                    gx_chunk_kernel<<<dim3(2048), dim3(256), 0, stream>>>(
                        (const half8*)eF, (const half8*)wpHi, (const half8*)wpLo,
                        gx, chunk);
                    for (int sc = 0; sc < RING; ++sc) {
                        int s = chunk * RING + sc;
                        const f16* hin  = hF + (size_t)(s & 1) * 65536;
                        f16*       hout = hF + (size_t)((s + 1) & 1) * 65536;
                        step_kernel<true><<<dim3(256), dim3(1024), 0, stream>>>(
                            hin, hout, (const half8*)eF,
                            (const half8*)wpHi, (const half8*)wpLo,
                            gx, bi, bf, bg, bo, c, h, s);
                    }
                }
            }
        } else {
            for (int s = 0; s < Sn; ++s) {
                const f16* hin  = hF + (size_t)(s & 1) * 65536;
                f16*       hout = hF + (size_t)((s + 1) & 1) * 65536;
                step_kernel<false><<<dim3(256), dim3(1024), 0, stream>>>(
                    hin, hout, (const half8*)eF,
                    (const half8*)wpHi, (const half8*)wpLo,
                    (const float*)nullptr, bi, bf, bg, bo, c, h, s);
            }
        }
        copy_hc<<<dim3(Bn * Hn / 256), dim3(256), 0, stream>>>(h, c, out);
        classifier<<<dim3(Bn * 2), dim3(64), 0, stream>>>(h, Vw, Vb, out);
    } else {
        float* hA = (float*)d_ws;
        float* cA = hA + Bn * Hn;
        float* hB = cA + Bn * Hn;
        float* cB = hB + Bn * Hn;
        hipMemsetAsync(d_ws, 0, (size_t)2 * Bn * Hn * sizeof(float), stream);
        for (int s = 0; s < Sn; ++s) {
            const float* hi = (s & 1) ? hB : hA;
            const float* ci = (s & 1) ? cB : cA;
            float* ho = (s & 1) ? hA : hB;
            float* co = (s & 1) ? cA : cB;
            lstm_step_fb<<<dim3(Hn / 4), dim3(256), 0, stream>>>(
                x, emb, Wxi, Wxf, Wxg, Wxo, bi, bf, bg, bo,
                Whi, Whf, Whg, Who, hi, ci, ho, co, s);
        }
        copy_hc<<<dim3(Bn * Hn / 256), dim3(256), 0, stream>>>(hA, cA, out);
        classifier<<<dim3(Bn * 2), dim3(64), 0, stream>>>(hA, Vw, Vb, out);
    }
}